// Round 6
// baseline (327.841 us; speedup 1.0000x reference)
//
#include <hip/hip_runtime.h>

#define NUSERS  6041
#define NMOVIES 3953
#define EMB     32
#define NGEN    18
#define H1N     64
#define H2N     32
#define H3N     16

typedef __bf16 bf16_t;
typedef bf16_t bf16x8 __attribute__((ext_vector_type(8)));
typedef float  f32x4  __attribute__((ext_vector_type(4)));

__device__ __forceinline__ f32x4 mfma16(bf16x8 a, bf16x8 b, f32x4 c) {
    return __builtin_amdgcn_mfma_f32_16x16x32_bf16(a, b, c, 0, 0, 0);
}
__device__ __forceinline__ unsigned pack2(float a, float b) {
    union { __bf16 h[2]; unsigned u; } p;
    p.h[0] = (bf16_t)a; p.h[1] = (bf16_t)b;
    return p.u;
}
// Compiler-level ordering fence: LDS writes (unsigned/bf16 stores) and reads
// (bf16x8 loads) are different TBAA types; without this the backend may hoist
// ds_read above the ds_write it depends on (observed: nondeterministic output
// across graph replays, absmax 0.0039 -> 0.0137). Zero runtime instructions;
// same-wave DS ops execute in order in hardware.
__device__ __forceinline__ void lds_fence() {
    __asm__ volatile("" ::: "memory");
    __builtin_amdgcn_sched_barrier(0);
}

// bf16 LDS buffers, per wave. Column-pair packing permutation:
// h1 col c (c<32): feature (c&1)*16 + (c>>1); c>=32: 32 + (c&1)*16 + ((c-32)>>1)
// h2 col c:        feature (c&1)*16 + (c>>1)
__device__ __forceinline__ int f1c(int c) {
    return (c < 32) ? ((c & 1) * 16 + (c >> 1)) : (32 + (c & 1) * 16 + ((c - 32) >> 1));
}
__device__ __forceinline__ int f2c(int c) { return (c & 1) * 16 + (c >> 1); }

#define H1C 72   // 64 + 8 pad cols (bf16) -> row stride 144 B (16B-aligned)
#define H2C 40   // 32 + 8  -> 80 B
#define H3C 24   // 16 + 8  -> 48 B

__global__ __launch_bounds__(256, 3)
void wd_fwd_v6(const int*   __restrict__ user_ids,
               const int*   __restrict__ movie_ids,
               const float* __restrict__ gender,
               const float* __restrict__ age,
               const float* __restrict__ occupation,
               const float* __restrict__ genres,
               const float* __restrict__ wide_W,
               const float* __restrict__ wide_b,
               const float* __restrict__ user_table,
               const float* __restrict__ movie_table,
               const float* __restrict__ W1,
               const float* __restrict__ b1,
               const float* __restrict__ W2,
               const float* __restrict__ b2,
               const float* __restrict__ W3,
               const float* __restrict__ b3,
               const float* __restrict__ W4,
               const float* __restrict__ b4,
               float*       __restrict__ out,
               int n)
{
    const int lane = threadIdx.x & 63;
    const int wib  = threadIdx.x >> 6;
    const int m    = lane & 15;
    const int quad = lane >> 4;

    __shared__ alignas(16) __bf16 sh1[4][16 * H1C];
    __shared__ alignas(16) __bf16 sh2[4][16 * H2C];
    __shared__ alignas(16) __bf16 sh3[4][16 * H3C];
    __bf16* __restrict__ h1p = sh1[wib];
    __bf16* __restrict__ h2p = sh2[wib];
    __bf16* __restrict__ h3p = sh3[wib];

    // ---------------- weight fragments (loop-invariant) ----------------
    // K-slot -> W1-row map for the rest K-tile (kt=2), permuted for contiguous loads:
    // quad0: genres 0..7 (rows 67+j), quad1: genres 8..15 (75+j),
    // quad2: {g16,g17,gender,age,occ,synth,0,0} = rows {83,84,64,65,66,-2,-1,-1}, quad3: none.
    int restrow[8];
    #pragma unroll
    for (int j = 0; j < 8; ++j) {
        int r = -1;
        if (quad == 0) r = 67 + j;
        if (quad == 1) r = 75 + j;
        if (quad == 2) {
            if (j == 0) r = 83;
            else if (j == 1) r = 84;
            else if (j == 2) r = 64;
            else if (j == 3) r = 65;
            else if (j == 4) r = 66;
            else if (j == 5) r = -2;   // -2 = synthetic wide feature
            else r = -1;
        }
        restrow[j] = r;
    }

    bf16x8 B1f[3][4];
    #pragma unroll
    for (int kt = 0; kt < 2; ++kt)
        #pragma unroll
        for (int nt = 0; nt < 4; ++nt) {
            bf16x8 f;
            #pragma unroll
            for (int j = 0; j < 8; ++j)
                f[j] = (bf16_t)W1[(kt * 32 + quad * 8 + j) * H1N + nt * 16 + m];
            B1f[kt][nt] = f;
        }
    #pragma unroll
    for (int nt = 0; nt < 4; ++nt) {
        bf16x8 f;
        #pragma unroll
        for (int j = 0; j < 8; ++j)
            f[j] = (restrow[j] >= 0) ? (bf16_t)W1[restrow[j] * H1N + nt * 16 + m] : (bf16_t)0.0f;
        B1f[2][nt] = f;
    }
    bf16x8 Bwf;   // wide vector as 1-col B over the rest K-tile
    {
        const float* wr = wide_W + NUSERS + NMOVIES;
        #pragma unroll
        for (int j = 0; j < 8; ++j) {
            float v = 0.0f;
            if (m == 0) {
                if (restrow[j] >= 0)       v = wr[restrow[j] - 64];
                else if (restrow[j] == -2) v = 1.0f;
            }
            Bwf[j] = (bf16_t)v;
        }
    }
    bf16x8 B2f[2][2];
    #pragma unroll
    for (int kt = 0; kt < 2; ++kt)
        #pragma unroll
        for (int nt = 0; nt < 2; ++nt) {
            bf16x8 f;
            #pragma unroll
            for (int j = 0; j < 8; ++j)
                f[j] = (bf16_t)W2[f1c(kt * 32 + quad * 8 + j) * H2N + nt * 16 + m];
            B2f[kt][nt] = f;
        }
    bf16x8 B3f;
    #pragma unroll
    for (int j = 0; j < 8; ++j) B3f[j] = (bf16_t)W3[f2c(quad * 8 + j) * H3N + m];
    bf16x8 Bw4;   // layer-4 weights as 1-col B (K=32, upper 16 zero)
    #pragma unroll
    for (int j = 0; j < 8; ++j) {
        const int k = quad * 8 + j;
        Bw4[j] = (m == 0 && k < H3N) ? (bf16_t)W4[k] : (bf16_t)0.0f;
    }

    float bias1[4], bias2[2];
    #pragma unroll
    for (int nt = 0; nt < 4; ++nt) bias1[nt] = b1[nt * 16 + m];
    #pragma unroll
    for (int nt = 0; nt < 2; ++nt) bias2[nt] = b2[nt * 16 + m];
    const float bias3 = b3[m];
    const float wb0   = wide_b[0];
    f32x4 cw_init;    // layer-4/wide C seed: b4 on col 0
    {
        const float b4v = b4[0];
        #pragma unroll
        for (int r = 0; r < 4; ++r) cw_init[r] = (m == 0) ? b4v : 0.0f;
    }

    // ---------------- pipeline ----------------
    const int ntiles = (n + 15) >> 4;
    const int gwave  = blockIdx.x * 4 + wib;
    const int nwaves = gridDim.x * 4;
    int niter = (gwave < ntiles) ? (ntiles - gwave + nwaves - 1) / nwaves : 0;

#define LOAD_IDS(tt, U, M) { int rr_ = (tt) * 16 + m; rr_ = rr_ < n ? rr_ : n - 1; \
                             U = user_ids[rr_]; M = movie_ids[rr_]; }
#define PREFETCH(tt, UID, MID, U0, U1, M0, M1, PF) { \
    const float4* up_ = (const float4*)(user_table + (size_t)(UID) * EMB + quad * 8); \
    U0 = up_[0]; U1 = up_[1]; \
    const float4* mp_ = (const float4*)(movie_table + (size_t)(MID) * EMB + quad * 8); \
    M0 = mp_[0]; M1 = mp_[1]; \
    int rr_ = (tt) * 16 + m; rr_ = rr_ < n ? rr_ : n - 1; \
    const float* grow_ = genres + (size_t)rr_ * NGEN; \
    if (quad < 2) { \
        const float2* g2_ = (const float2*)(grow_ + quad * 8); \
        PF[0] = g2_[0]; PF[1] = g2_[1]; PF[2] = g2_[2]; PF[3] = g2_[3]; \
    } else if (quad == 2) { \
        PF[0] = ((const float2*)(grow_ + 16))[0]; \
        PF[1] = make_float2(gender[rr_], age[rr_]); \
        PF[2] = make_float2(occupation[rr_], wide_W[UID]); \
        PF[3] = make_float2(wide_W[NUSERS + (MID)], 0.0f); \
    } \
}

    if (niter > 0) {
        int t_c = gwave;
        int t_n = (niter > 1) ? t_c + nwaves : t_c;

        int uidc, midc, uidn, midn, uidn2, midn2;
        float4 U0c, U1c, M0c, M1c, U0n, U1n, M0n, M1n;
        float2 pfc[4] = {}, pfn[4] = {};

        LOAD_IDS(t_c, uidc, midc);
        LOAD_IDS(t_n, uidn, midn);
        PREFETCH(t_c, uidc, midc, U0c, U1c, M0c, M1c, pfc);
        uidn2 = uidn; midn2 = midn;

        for (int i = 0; i < niter; ++i) {
            const bool more = (i + 1 < niter);
            int t_n2 = t_n;
            if (more) {
                PREFETCH(t_n, uidn, midn, U0n, U1n, M0n, M1n, pfn);
                t_n2 = t_n + nwaves; if (t_n2 >= ntiles) t_n2 = t_n;
                LOAD_IDS(t_n2, uidn2, midn2);
            }

            // -------- compute tile t_c --------
            const int base = t_c << 4;

            bf16x8 A0, A1, A2;
            A0[0]=(bf16_t)U0c.x; A0[1]=(bf16_t)U0c.y; A0[2]=(bf16_t)U0c.z; A0[3]=(bf16_t)U0c.w;
            A0[4]=(bf16_t)U1c.x; A0[5]=(bf16_t)U1c.y; A0[6]=(bf16_t)U1c.z; A0[7]=(bf16_t)U1c.w;
            A1[0]=(bf16_t)M0c.x; A1[1]=(bf16_t)M0c.y; A1[2]=(bf16_t)M0c.z; A1[3]=(bf16_t)M0c.w;
            A1[4]=(bf16_t)M1c.x; A1[5]=(bf16_t)M1c.y; A1[6]=(bf16_t)M1c.z; A1[7]=(bf16_t)M1c.w;
            {
                float a0 = pfc[0].x, a1 = pfc[0].y, a2 = pfc[1].x, a3 = pfc[1].y;
                float a4 = pfc[2].x, a5 = pfc[2].y, a6 = pfc[3].x, a7 = pfc[3].y;
                if (quad == 2) { a5 = pfc[2].y + pfc[3].x + wb0; a6 = 0.0f; a7 = 0.0f; }
                if (quad == 3) { a0=a1=a2=a3=a4=a5=a6=a7 = 0.0f; }
                A2[0]=(bf16_t)a0; A2[1]=(bf16_t)a1; A2[2]=(bf16_t)a2; A2[3]=(bf16_t)a3;
                A2[4]=(bf16_t)a4; A2[5]=(bf16_t)a5; A2[6]=(bf16_t)a6; A2[7]=(bf16_t)a7;
            }

            // wide (+b4 seed) as 1-col MFMA on the rest K-tile
            f32x4 accw = mfma16(A2, Bwf, cw_init);

            // layer 1
            f32x4 acc[4];
            #pragma unroll
            for (int nt = 0; nt < 4; ++nt) {
                f32x4 c = {bias1[nt], bias1[nt], bias1[nt], bias1[nt]};
                c = mfma16(A0, B1f[0][nt], c);
                c = mfma16(A1, B1f[1][nt], c);
                c = mfma16(A2, B1f[2][nt], c);
                acc[nt] = c;
            }
            // relu + pack col-pairs -> bf16 LDS (8 b32 writes)
            #pragma unroll
            for (int r = 0; r < 4; ++r) {
                const int row = quad * 4 + r;
                *(unsigned*)&h1p[row * H1C + 2 * m] =
                    pack2(fmaxf(acc[0][r], 0.0f), fmaxf(acc[1][r], 0.0f));
                *(unsigned*)&h1p[row * H1C + 32 + 2 * m] =
                    pack2(fmaxf(acc[2][r], 0.0f), fmaxf(acc[3][r], 0.0f));
            }
            lds_fence();                 // order: h1 writes before h1 reads

            bf16x8 AL2[2];
            AL2[0] = *(const bf16x8*)&h1p[m * H1C + quad * 8];
            AL2[1] = *(const bf16x8*)&h1p[m * H1C + 32 + quad * 8];

            // layer 2
            f32x4 acc2[2];
            #pragma unroll
            for (int nt = 0; nt < 2; ++nt) {
                f32x4 c = {bias2[nt], bias2[nt], bias2[nt], bias2[nt]};
                c = mfma16(AL2[0], B2f[0][nt], c);
                c = mfma16(AL2[1], B2f[1][nt], c);
                acc2[nt] = c;
            }
            #pragma unroll
            for (int r = 0; r < 4; ++r) {
                const int row = quad * 4 + r;
                *(unsigned*)&h2p[row * H2C + 2 * m] =
                    pack2(fmaxf(acc2[0][r], 0.0f), fmaxf(acc2[1][r], 0.0f));
            }
            lds_fence();                 // order: h2 writes before h2 read

            bf16x8 AL3 = *(const bf16x8*)&h2p[m * H2C + quad * 8];

            // layer 3
            f32x4 acc3 = mfma16(AL3, B3f, (f32x4){bias3, bias3, bias3, bias3});
            #pragma unroll
            for (int r = 0; r < 4; ++r)
                h3p[(quad * 4 + r) * H3C + m] = (bf16_t)fmaxf(acc3[r], 0.0f);
            lds_fence();                 // order: h3 writes before h3 read

            bf16x8 A4 = {};
            if (quad < 2) A4 = *(const bf16x8*)&h3p[m * H3C + quad * 8];
            lds_fence();                 // order: h3 read before next iter's writes

            // layer 4 + wide + b4 in one MFMA (C = accw)
            f32x4 z4 = mfma16(A4, Bw4, accw);

            if (m == 0) {
                const int ob = base + quad * 4;
                float4 o;
                o.x = 1.0f / (1.0f + __expf(-z4[0]));
                o.y = 1.0f / (1.0f + __expf(-z4[1]));
                o.z = 1.0f / (1.0f + __expf(-z4[2]));
                o.w = 1.0f / (1.0f + __expf(-z4[3]));
                if (ob + 3 < n) {
                    *(float4*)(out + ob) = o;
                } else {
                    if (ob     < n) out[ob]     = o.x;
                    if (ob + 1 < n) out[ob + 1] = o.y;
                    if (ob + 2 < n) out[ob + 2] = o.z;
                }
            }

            // -------- rotate pipeline --------
            if (more) {
                U0c = U0n; U1c = U1n; M0c = M0n; M1c = M1n;
                pfc[0] = pfn[0]; pfc[1] = pfn[1]; pfc[2] = pfn[2]; pfc[3] = pfn[3];
                uidn = uidn2; midn = midn2;
                t_c = t_n; t_n = t_n2;
            }
        }
    }
#undef LOAD_IDS
#undef PREFETCH
}

extern "C" void kernel_launch(void* const* d_in, const int* in_sizes, int n_in,
                              void* d_out, int out_size, void* d_ws, size_t ws_size,
                              hipStream_t stream)
{
    const int*   user_ids   = (const int*)  d_in[0];
    const int*   movie_ids  = (const int*)  d_in[1];
    const float* gender     = (const float*)d_in[2];
    const float* age        = (const float*)d_in[3];
    const float* occupation = (const float*)d_in[4];
    const float* genres     = (const float*)d_in[5];
    const float* wide_W     = (const float*)d_in[6];
    const float* wide_b     = (const float*)d_in[7];
    const float* user_table = (const float*)d_in[8];
    const float* movie_table= (const float*)d_in[9];
    const float* W1         = (const float*)d_in[10];
    const float* b1         = (const float*)d_in[11];
    const float* W2         = (const float*)d_in[12];
    const float* b2         = (const float*)d_in[13];
    const float* W3         = (const float*)d_in[14];
    const float* b3         = (const float*)d_in[15];
    const float* W4         = (const float*)d_in[16];
    const float* b4         = (const float*)d_in[17];
    float*       out        = (float*)d_out;

    const int n = in_sizes[0];
    wd_fwd_v6<<<768, 256, 0, stream>>>(user_ids, movie_ids, gender, age, occupation,
                                       genres, wide_W, wide_b, user_table, movie_table,
                                       W1, b1, W2, b2, W3, b3, W4, b4, out, n);
}

// Round 7
// 218.207 us; speedup vs baseline: 1.5024x; 1.5024x over previous
//
#include <hip/hip_runtime.h>

#define NUSERS  6041
#define NMOVIES 3953
#define EMB     32
#define NGEN    18
#define H1N     64
#define H2N     32
#define H3N     16

typedef __bf16 bf16_t;
typedef bf16_t bf16x8 __attribute__((ext_vector_type(8)));
typedef float  f32x4  __attribute__((ext_vector_type(4)));

__device__ __forceinline__ f32x4 mfma16(bf16x8 a, bf16x8 b, f32x4 c) {
    return __builtin_amdgcn_mfma_f32_16x16x32_bf16(a, b, c, 0, 0, 0);
}
__device__ __forceinline__ unsigned pack2(float a, float b) {
    union { __bf16 h[2]; unsigned u; } p;
    p.h[0] = (bf16_t)a; p.h[1] = (bf16_t)b;
    return p.u;
}
// Compiler-level ordering fence: LDS writes (unsigned/bf16 stores) and reads
// (bf16x8 loads) are different TBAA types; without this the backend may hoist
// ds_read above the ds_write it depends on (observed r5: nondeterministic
// output across graph replays). Zero runtime instructions; same-wave DS ops
// execute in order in hardware.
__device__ __forceinline__ void lds_fence() {
    __asm__ volatile("" ::: "memory");
    __builtin_amdgcn_sched_barrier(0);
}

// bf16 LDS buffers, per wave. Column-pair packing permutation:
// h1 col c (c<32): feature (c&1)*16 + (c>>1); c>=32: 32 + (c&1)*16 + ((c-32)>>1)
// h2 col c:        feature (c&1)*16 + (c>>1)
__device__ __forceinline__ int f1c(int c) {
    return (c < 32) ? ((c & 1) * 16 + (c >> 1)) : (32 + (c & 1) * 16 + ((c - 32) >> 1));
}
__device__ __forceinline__ int f2c(int c) { return (c & 1) * 16 + (c >> 1); }

#define H1C 72   // 64 + 8 pad cols (bf16) -> row stride 144 B (16B-aligned)
#define H2C 40   // 32 + 8  -> 80 B
#define H3C 24   // 16 + 8  -> 48 B

// NOTE r6 lesson: __launch_bounds__(256, 3) capped the allocator below the
// ~150-VGPR live set (weight frags + pipeline staging) -> hot-loop scratch
// spills -> FETCH 451 MB / WRITE 81 MB (5.5x ideal bytes), 209 us. No bound:
// allocator keeps everything resident (r3 precedent: VGPR 120, FETCH ~ ideal).
__global__ __launch_bounds__(256)
void wd_fwd_v7(const int*   __restrict__ user_ids,
               const int*   __restrict__ movie_ids,
               const float* __restrict__ gender,
               const float* __restrict__ age,
               const float* __restrict__ occupation,
               const float* __restrict__ genres,
               const float* __restrict__ wide_W,
               const float* __restrict__ wide_b,
               const float* __restrict__ user_table,
               const float* __restrict__ movie_table,
               const float* __restrict__ W1,
               const float* __restrict__ b1,
               const float* __restrict__ W2,
               const float* __restrict__ b2,
               const float* __restrict__ W3,
               const float* __restrict__ b3,
               const float* __restrict__ W4,
               const float* __restrict__ b4,
               float*       __restrict__ out,
               int n)
{
    const int lane = threadIdx.x & 63;
    const int wib  = threadIdx.x >> 6;
    const int m    = lane & 15;
    const int quad = lane >> 4;

    __shared__ alignas(16) __bf16 sh1[4][16 * H1C];
    __shared__ alignas(16) __bf16 sh2[4][16 * H2C];
    __shared__ alignas(16) __bf16 sh3[4][16 * H3C];
    __bf16* __restrict__ h1p = sh1[wib];
    __bf16* __restrict__ h2p = sh2[wib];
    __bf16* __restrict__ h3p = sh3[wib];

    // ---------------- weight fragments (loop-invariant) ----------------
    // K-slot -> W1-row map for the rest K-tile (kt=2), permuted for contiguous loads:
    // quad0: genres 0..7 (rows 67+j), quad1: genres 8..15 (75+j),
    // quad2: {g16,g17,gender,age,occ,synth,0,0} = rows {83,84,64,65,66,-2,-1,-1}, quad3: none.
    int restrow[8];
    #pragma unroll
    for (int j = 0; j < 8; ++j) {
        int r = -1;
        if (quad == 0) r = 67 + j;
        if (quad == 1) r = 75 + j;
        if (quad == 2) {
            if (j == 0) r = 83;
            else if (j == 1) r = 84;
            else if (j == 2) r = 64;
            else if (j == 3) r = 65;
            else if (j == 4) r = 66;
            else if (j == 5) r = -2;   // -2 = synthetic wide feature
            else r = -1;
        }
        restrow[j] = r;
    }

    bf16x8 B1f[3][4];
    #pragma unroll
    for (int kt = 0; kt < 2; ++kt)
        #pragma unroll
        for (int nt = 0; nt < 4; ++nt) {
            bf16x8 f;
            #pragma unroll
            for (int j = 0; j < 8; ++j)
                f[j] = (bf16_t)W1[(kt * 32 + quad * 8 + j) * H1N + nt * 16 + m];
            B1f[kt][nt] = f;
        }
    #pragma unroll
    for (int nt = 0; nt < 4; ++nt) {
        bf16x8 f;
        #pragma unroll
        for (int j = 0; j < 8; ++j)
            f[j] = (restrow[j] >= 0) ? (bf16_t)W1[restrow[j] * H1N + nt * 16 + m] : (bf16_t)0.0f;
        B1f[2][nt] = f;
    }
    bf16x8 Bwf;   // wide vector as 1-col B over the rest K-tile
    {
        const float* wr = wide_W + NUSERS + NMOVIES;
        #pragma unroll
        for (int j = 0; j < 8; ++j) {
            float v = 0.0f;
            if (m == 0) {
                if (restrow[j] >= 0)       v = wr[restrow[j] - 64];
                else if (restrow[j] == -2) v = 1.0f;
            }
            Bwf[j] = (bf16_t)v;
        }
    }
    bf16x8 B2f[2][2];
    #pragma unroll
    for (int kt = 0; kt < 2; ++kt)
        #pragma unroll
        for (int nt = 0; nt < 2; ++nt) {
            bf16x8 f;
            #pragma unroll
            for (int j = 0; j < 8; ++j)
                f[j] = (bf16_t)W2[f1c(kt * 32 + quad * 8 + j) * H2N + nt * 16 + m];
            B2f[kt][nt] = f;
        }
    bf16x8 B3f;
    #pragma unroll
    for (int j = 0; j < 8; ++j) B3f[j] = (bf16_t)W3[f2c(quad * 8 + j) * H3N + m];
    bf16x8 Bw4;   // layer-4 weights as 1-col B (K=32, upper 16 zero)
    #pragma unroll
    for (int j = 0; j < 8; ++j) {
        const int k = quad * 8 + j;
        Bw4[j] = (m == 0 && k < H3N) ? (bf16_t)W4[k] : (bf16_t)0.0f;
    }

    float bias1[4], bias2[2];
    #pragma unroll
    for (int nt = 0; nt < 4; ++nt) bias1[nt] = b1[nt * 16 + m];
    #pragma unroll
    for (int nt = 0; nt < 2; ++nt) bias2[nt] = b2[nt * 16 + m];
    const float bias3 = b3[m];
    const float wb0   = wide_b[0];
    f32x4 cw_init;    // layer-4/wide C seed: b4 on col 0
    {
        const float b4v = b4[0];
        #pragma unroll
        for (int r = 0; r < 4; ++r) cw_init[r] = (m == 0) ? b4v : 0.0f;
    }

    // ---------------- pipeline ----------------
    const int ntiles = (n + 15) >> 4;
    const int gwave  = blockIdx.x * 4 + wib;
    const int nwaves = gridDim.x * 4;
    int niter = (gwave < ntiles) ? (ntiles - gwave + nwaves - 1) / nwaves : 0;

#define LOAD_IDS(tt, U, M) { int rr_ = (tt) * 16 + m; rr_ = rr_ < n ? rr_ : n - 1; \
                             U = user_ids[rr_]; M = movie_ids[rr_]; }
#define PREFETCH(tt, UID, MID, U0, U1, M0, M1, PF) { \
    const float4* up_ = (const float4*)(user_table + (size_t)(UID) * EMB + quad * 8); \
    U0 = up_[0]; U1 = up_[1]; \
    const float4* mp_ = (const float4*)(movie_table + (size_t)(MID) * EMB + quad * 8); \
    M0 = mp_[0]; M1 = mp_[1]; \
    int rr_ = (tt) * 16 + m; rr_ = rr_ < n ? rr_ : n - 1; \
    const float* grow_ = genres + (size_t)rr_ * NGEN; \
    if (quad < 2) { \
        const float2* g2_ = (const float2*)(grow_ + quad * 8); \
        PF[0] = g2_[0]; PF[1] = g2_[1]; PF[2] = g2_[2]; PF[3] = g2_[3]; \
    } else if (quad == 2) { \
        PF[0] = ((const float2*)(grow_ + 16))[0]; \
        PF[1] = make_float2(gender[rr_], age[rr_]); \
        PF[2] = make_float2(occupation[rr_], wide_W[UID]); \
        PF[3] = make_float2(wide_W[NUSERS + (MID)], 0.0f); \
    } \
}

    if (niter > 0) {
        int t_c = gwave;
        int t_n = (niter > 1) ? t_c + nwaves : t_c;

        int uidc, midc, uidn, midn, uidn2, midn2;
        float4 U0c, U1c, M0c, M1c, U0n, U1n, M0n, M1n;
        float2 pfc[4] = {}, pfn[4] = {};

        LOAD_IDS(t_c, uidc, midc);
        LOAD_IDS(t_n, uidn, midn);
        PREFETCH(t_c, uidc, midc, U0c, U1c, M0c, M1c, pfc);
        uidn2 = uidn; midn2 = midn;

        for (int i = 0; i < niter; ++i) {
            const bool more = (i + 1 < niter);
            int t_n2 = t_n;
            if (more) {
                PREFETCH(t_n, uidn, midn, U0n, U1n, M0n, M1n, pfn);
                t_n2 = t_n + nwaves; if (t_n2 >= ntiles) t_n2 = t_n;
                LOAD_IDS(t_n2, uidn2, midn2);
            }

            // -------- compute tile t_c --------
            const int base = t_c << 4;

            bf16x8 A0, A1, A2;
            A0[0]=(bf16_t)U0c.x; A0[1]=(bf16_t)U0c.y; A0[2]=(bf16_t)U0c.z; A0[3]=(bf16_t)U0c.w;
            A0[4]=(bf16_t)U1c.x; A0[5]=(bf16_t)U1c.y; A0[6]=(bf16_t)U1c.z; A0[7]=(bf16_t)U1c.w;
            A1[0]=(bf16_t)M0c.x; A1[1]=(bf16_t)M0c.y; A1[2]=(bf16_t)M0c.z; A1[3]=(bf16_t)M0c.w;
            A1[4]=(bf16_t)M1c.x; A1[5]=(bf16_t)M1c.y; A1[6]=(bf16_t)M1c.z; A1[7]=(bf16_t)M1c.w;
            {
                float a0 = pfc[0].x, a1 = pfc[0].y, a2 = pfc[1].x, a3 = pfc[1].y;
                float a4 = pfc[2].x, a5 = pfc[2].y, a6 = pfc[3].x, a7 = pfc[3].y;
                if (quad == 2) { a5 = pfc[2].y + pfc[3].x + wb0; a6 = 0.0f; a7 = 0.0f; }
                if (quad == 3) { a0=a1=a2=a3=a4=a5=a6=a7 = 0.0f; }
                A2[0]=(bf16_t)a0; A2[1]=(bf16_t)a1; A2[2]=(bf16_t)a2; A2[3]=(bf16_t)a3;
                A2[4]=(bf16_t)a4; A2[5]=(bf16_t)a5; A2[6]=(bf16_t)a6; A2[7]=(bf16_t)a7;
            }

            // wide (+b4 seed) as 1-col MFMA on the rest K-tile
            f32x4 accw = mfma16(A2, Bwf, cw_init);

            // layer 1
            f32x4 acc[4];
            #pragma unroll
            for (int nt = 0; nt < 4; ++nt) {
                f32x4 c = {bias1[nt], bias1[nt], bias1[nt], bias1[nt]};
                c = mfma16(A0, B1f[0][nt], c);
                c = mfma16(A1, B1f[1][nt], c);
                c = mfma16(A2, B1f[2][nt], c);
                acc[nt] = c;
            }
            // relu + pack col-pairs -> bf16 LDS (8 b32 writes)
            #pragma unroll
            for (int r = 0; r < 4; ++r) {
                const int row = quad * 4 + r;
                *(unsigned*)&h1p[row * H1C + 2 * m] =
                    pack2(fmaxf(acc[0][r], 0.0f), fmaxf(acc[1][r], 0.0f));
                *(unsigned*)&h1p[row * H1C + 32 + 2 * m] =
                    pack2(fmaxf(acc[2][r], 0.0f), fmaxf(acc[3][r], 0.0f));
            }
            lds_fence();                 // order: h1 writes before h1 reads

            bf16x8 AL2[2];
            AL2[0] = *(const bf16x8*)&h1p[m * H1C + quad * 8];
            AL2[1] = *(const bf16x8*)&h1p[m * H1C + 32 + quad * 8];

            // layer 2
            f32x4 acc2[2];
            #pragma unroll
            for (int nt = 0; nt < 2; ++nt) {
                f32x4 c = {bias2[nt], bias2[nt], bias2[nt], bias2[nt]};
                c = mfma16(AL2[0], B2f[0][nt], c);
                c = mfma16(AL2[1], B2f[1][nt], c);
                acc2[nt] = c;
            }
            #pragma unroll
            for (int r = 0; r < 4; ++r) {
                const int row = quad * 4 + r;
                *(unsigned*)&h2p[row * H2C + 2 * m] =
                    pack2(fmaxf(acc2[0][r], 0.0f), fmaxf(acc2[1][r], 0.0f));
            }
            lds_fence();                 // order: h2 writes before h2 read

            bf16x8 AL3 = *(const bf16x8*)&h2p[m * H2C + quad * 8];

            // layer 3
            f32x4 acc3 = mfma16(AL3, B3f, (f32x4){bias3, bias3, bias3, bias3});
            #pragma unroll
            for (int r = 0; r < 4; ++r)
                h3p[(quad * 4 + r) * H3C + m] = (bf16_t)fmaxf(acc3[r], 0.0f);
            lds_fence();                 // order: h3 writes before h3 read

            bf16x8 A4 = {};
            if (quad < 2) A4 = *(const bf16x8*)&h3p[m * H3C + quad * 8];
            lds_fence();                 // order: h3 read before next iter's writes

            // layer 4 + wide + b4 in one MFMA (C = accw)
            f32x4 z4 = mfma16(A4, Bw4, accw);

            if (m == 0) {
                const int ob = base + quad * 4;
                float4 o;
                o.x = 1.0f / (1.0f + __expf(-z4[0]));
                o.y = 1.0f / (1.0f + __expf(-z4[1]));
                o.z = 1.0f / (1.0f + __expf(-z4[2]));
                o.w = 1.0f / (1.0f + __expf(-z4[3]));
                if (ob + 3 < n) {
                    *(float4*)(out + ob) = o;
                } else {
                    if (ob     < n) out[ob]     = o.x;
                    if (ob + 1 < n) out[ob + 1] = o.y;
                    if (ob + 2 < n) out[ob + 2] = o.z;
                }
            }

            // -------- rotate pipeline --------
            if (more) {
                U0c = U0n; U1c = U1n; M0c = M0n; M1c = M1n;
                pfc[0] = pfn[0]; pfc[1] = pfn[1]; pfc[2] = pfn[2]; pfc[3] = pfn[3];
                uidn = uidn2; midn = midn2;
                t_c = t_n; t_n = t_n2;
            }
        }
    }
#undef LOAD_IDS
#undef PREFETCH
}

extern "C" void kernel_launch(void* const* d_in, const int* in_sizes, int n_in,
                              void* d_out, int out_size, void* d_ws, size_t ws_size,
                              hipStream_t stream)
{
    const int*   user_ids   = (const int*)  d_in[0];
    const int*   movie_ids  = (const int*)  d_in[1];
    const float* gender     = (const float*)d_in[2];
    const float* age        = (const float*)d_in[3];
    const float* occupation = (const float*)d_in[4];
    const float* genres     = (const float*)d_in[5];
    const float* wide_W     = (const float*)d_in[6];
    const float* wide_b     = (const float*)d_in[7];
    const float* user_table = (const float*)d_in[8];
    const float* movie_table= (const float*)d_in[9];
    const float* W1         = (const float*)d_in[10];
    const float* b1         = (const float*)d_in[11];
    const float* W2         = (const float*)d_in[12];
    const float* b2         = (const float*)d_in[13];
    const float* W3         = (const float*)d_in[14];
    const float* b3         = (const float*)d_in[15];
    const float* W4         = (const float*)d_in[16];
    const float* b4         = (const float*)d_in[17];
    float*       out        = (float*)d_out;

    const int n = in_sizes[0];
    wd_fwd_v7<<<1024, 256, 0, stream>>>(user_ids, movie_ids, gender, age, occupation,
                                        genres, wide_W, wide_b, user_table, movie_table,
                                        W1, b1, W2, b2, W3, b3, W4, b4, out, n);
}